// Round 1
// baseline (1258.641 us; speedup 1.0000x reference)
//
#include <hip/hip_runtime.h>

namespace {

constexpr int kB = 64;
constexpr int kP = 25000;
constexpr int kT = 16;
constexpr int kC = 81;
constexpr int kRowsPerBlk = 64;   // ce_kernel rows per block
constexpr float kThresh = 0.5f;

__device__ __forceinline__ float smooth_l1(float d) {
  float ad = fabsf(d);
  return ad < 1.0f ? 0.5f * d * d : ad - 0.5f;
}

// ---------------------------------------------------------------------------
// Kernel A: per-batch matching + localization loss.
// One block (256 threads) per batch element.
// ---------------------------------------------------------------------------
__global__ __launch_bounds__(256) void match_kernel(
    const float* __restrict__ loc_data,   // [B,P,4]
    const float* __restrict__ priors,     // [P,4] (cx,cy,w,h)
    const float* __restrict__ targets,    // [B,T,5]
    unsigned char* __restrict__ conf_t,   // [B,P] out
    int* __restrict__ num_pos,            // [B] out
    float* __restrict__ loss_l_acc) {     // [1] accumulate
  const int b = blockIdx.x;
  const int tid = threadIdx.x;

  __shared__ float tx0[kT], ty0[kT], tx1[kT], ty1[kT], tlab[kT], tarea[kT];
  __shared__ int s_bp[kT];
  __shared__ float smax[kT][256];
  __shared__ int sidx[kT][256];

  if (tid < kT) {
    const float* tg = targets + (b * kT + tid) * 5;
    float x0 = tg[0], y0 = tg[1], x1 = tg[2], y1 = tg[3];
    tx0[tid] = x0; ty0[tid] = y0; tx1[tid] = x1; ty1[tid] = y1;
    tlab[tid] = tg[4];
    tarea[tid] = (x1 - x0) * (y1 - y0);
  }
  __syncthreads();

  // Pass 1: per-truth argmax over priors (first-occurrence tie-break).
  float bestv[kT];
  int besti[kT];
#pragma unroll
  for (int t = 0; t < kT; ++t) { bestv[t] = -1.0f; besti[t] = 0; }

  for (int p = tid; p < kP; p += 256) {
    float4 pr = reinterpret_cast<const float4*>(priors)[p];
    float px0 = pr.x - pr.z * 0.5f, py0 = pr.y - pr.w * 0.5f;
    float px1 = pr.x + pr.z * 0.5f, py1 = pr.y + pr.w * 0.5f;
    float parea = (px1 - px0) * (py1 - py0);
#pragma unroll
    for (int t = 0; t < kT; ++t) {
      float lx = fmaxf(tx0[t], px0), ly = fmaxf(ty0[t], py0);
      float rx = fminf(tx1[t], px1), ry = fminf(ty1[t], py1);
      float w = fmaxf(rx - lx, 0.0f), h = fmaxf(ry - ly, 0.0f);
      float inter = w * h;
      float iou = inter / (tarea[t] + parea - inter);
      if (iou > bestv[t]) { bestv[t] = iou; besti[t] = p; }  // strict >: first idx wins
    }
  }
#pragma unroll
  for (int t = 0; t < kT; ++t) { smax[t][tid] = bestv[t]; sidx[t][tid] = besti[t]; }
  __syncthreads();
  for (int s = 128; s > 0; s >>= 1) {
    if (tid < s) {
#pragma unroll
      for (int t = 0; t < kT; ++t) {
        float v1 = smax[t][tid], v2 = smax[t][tid + s];
        int i1 = sidx[t][tid], i2 = sidx[t][tid + s];
        if (v2 > v1 || (v2 == v1 && i2 < i1)) { smax[t][tid] = v2; sidx[t][tid] = i2; }
      }
    }
    __syncthreads();
  }
  if (tid < kT) s_bp[tid] = sidx[tid][0];
  __syncthreads();

  // Pass 2: per-prior best truth, forcing, conf, encode, smooth-L1.
  float lsum = 0.0f;
  int pcount = 0;
  for (int p = tid; p < kP; p += 256) {
    float4 pr = reinterpret_cast<const float4*>(priors)[p];
    float px0 = pr.x - pr.z * 0.5f, py0 = pr.y - pr.w * 0.5f;
    float px1 = pr.x + pr.z * 0.5f, py1 = pr.y + pr.w * 0.5f;
    float parea = (px1 - px0) * (py1 - py0);
    float mv = -1.0f;
    int mt = 0;
#pragma unroll
    for (int t = 0; t < kT; ++t) {
      float lx = fmaxf(tx0[t], px0), ly = fmaxf(ty0[t], py0);
      float rx = fminf(tx1[t], px1), ry = fminf(ty1[t], py1);
      float w = fmaxf(rx - lx, 0.0f), h = fmaxf(ry - ly, 0.0f);
      float inter = w * h;
      float iou = inter / (tarea[t] + parea - inter);
      if (iou > mv) { mv = iou; mt = t; }  // first occurrence on ties
    }
    bool forced = false;
#pragma unroll
    for (int j = 0; j < kT; ++j) {        // ascending j: last wins (torch loop order)
      if (s_bp[j] == p) { mt = j; forced = true; }
    }
    int conf = (!forced && (mv < kThresh)) ? 0 : ((int)tlab[mt] + 1);
    conf_t[b * kP + p] = (unsigned char)conf;
    if (conf > 0) {
      ++pcount;
      float mx0 = tx0[mt], my0 = ty0[mt], mx1 = tx1[mt], my1 = ty1[mt];
      float gcx = ((mx0 + mx1) * 0.5f - pr.x) / (0.1f * pr.z);
      float gcy = ((my0 + my1) * 0.5f - pr.y) / (0.1f * pr.w);
      float gw = logf((mx1 - mx0) / pr.z) / 0.2f;
      float gh = logf((my1 - my0) / pr.w) / 0.2f;
      float4 ld = reinterpret_cast<const float4*>(loc_data)[b * kP + p];
      lsum += smooth_l1(ld.x - gcx) + smooth_l1(ld.y - gcy) +
              smooth_l1(ld.z - gw) + smooth_l1(ld.w - gh);
    }
  }
  __syncthreads();
  smax[0][tid] = lsum;
  sidx[0][tid] = pcount;
  __syncthreads();
  for (int s = 128; s > 0; s >>= 1) {
    if (tid < s) { smax[0][tid] += smax[0][tid + s]; sidx[0][tid] += sidx[0][tid + s]; }
    __syncthreads();
  }
  if (tid == 0) {
    num_pos[b] = sidx[0][0];
    atomicAdd(loss_l_acc, smax[0][0]);
  }
}

// ---------------------------------------------------------------------------
// Kernel B: per-(b,p) cross-entropy via logsumexp. LDS-staged float4 loads.
// Grid = B*P/kRowsPerBlk blocks x 256 threads.
// ---------------------------------------------------------------------------
__global__ __launch_bounds__(256) void ce_kernel(
    const float* __restrict__ conf_data,      // [B*P, 81]
    const unsigned char* __restrict__ conf_t, // [B*P]
    float* __restrict__ loss_c,               // [B*P] out (0 at positives)
    float* __restrict__ pos_ce_acc) {         // [1] accumulate
  __shared__ float tile[kRowsPerBlk * kC];    // 20736 B
  const int tid = threadIdx.x;
  const long long base = (long long)blockIdx.x * (kRowsPerBlk * kC);
  const float4* src = reinterpret_cast<const float4*>(conf_data + base);
  float4* dst = reinterpret_cast<float4*>(tile);
  for (int i = tid; i < kRowsPerBlk * kC / 4; i += 256) dst[i] = src[i];
  __syncthreads();

  if (tid < kRowsPerBlk) {
    const int row = blockIdx.x * kRowsPerBlk + tid;
    const float* x = tile + tid * kC;  // stride 81 (odd*... 81 mod 32 = 17 -> conflict-free perm)
    float m = x[0];
    for (int j = 1; j < kC; ++j) m = fmaxf(m, x[j]);
    float s = 0.0f;
    for (int j = 0; j < kC; ++j) s += __expf(x[j] - m);
    float lse = __logf(s) + m;
    int ct = conf_t[row];
    float ce = lse - x[ct];
    bool pos = ct > 0;
    loss_c[row] = pos ? 0.0f : ce;
    float posce = pos ? ce : 0.0f;
    // one full wave (lanes 0..63): shuffle reduce
    for (int off = 32; off > 0; off >>= 1) posce += __shfl_down(posce, off, 64);
    if (tid == 0) atomicAdd(pos_ce_acc, posce);
  }
}

// ---------------------------------------------------------------------------
// Kernel C: per-batch exact top-k sum of loss_c via 8-bit radix select.
// All loss_c >= 0, so raw float bits order as unsigned ints.
// ---------------------------------------------------------------------------
__global__ __launch_bounds__(256) void select_kernel(
    const float* __restrict__ loss_c,  // [B,P]
    const int* __restrict__ num_pos,   // [B]
    float* __restrict__ neg_ce_acc) {  // [1] accumulate
  const int b = blockIdx.x;
  const int tid = threadIdx.x;
  const float* vals = loss_c + b * kP;
  const int k = min(3 * num_pos[b], kP - 1);
  if (k <= 0) return;  // uniform branch

  __shared__ unsigned int hist[256];
  __shared__ unsigned int s_prefix;
  __shared__ int s_k;
  __shared__ float sred[256];

  unsigned int prefix = 0;
  int kk = k;
  for (int pass = 0; pass < 4; ++pass) {
    const int shift = 24 - pass * 8;
    const unsigned int mask = (pass == 0) ? 0u : (0xFFFFFFFFu << (shift + 8));
    hist[tid] = 0;
    __syncthreads();
    for (int p = tid; p < kP; p += 256) {
      unsigned int u = __float_as_uint(vals[p]);
      if ((u & mask) == prefix) atomicAdd(&hist[(u >> shift) & 255], 1u);
    }
    __syncthreads();
    if (tid == 0) {
      int acc = 0, d = 255;
      for (; d > 0; --d) {
        int c = (int)hist[d];
        if (acc + c >= kk) break;
        acc += c;
      }
      s_k = kk - acc;
      s_prefix = prefix | ((unsigned int)d << shift);
    }
    __syncthreads();
    prefix = s_prefix;
    kk = s_k;
    __syncthreads();
  }
  // prefix = bit pattern of k-th largest value; kk copies of it are selected.
  float sum = 0.0f;
  for (int p = tid; p < kP; p += 256) {
    float v = vals[p];
    if (__float_as_uint(v) > prefix) sum += v;
  }
  sred[tid] = sum;
  __syncthreads();
  for (int s = 128; s > 0; s >>= 1) {
    if (tid < s) sred[tid] += sred[tid + s];
    __syncthreads();
  }
  if (tid == 0) {
    atomicAdd(neg_ce_acc, sred[0] + (float)kk * __uint_as_float(prefix));
  }
}

// ---------------------------------------------------------------------------
// Kernel D: finalize the two scalar outputs.
// ---------------------------------------------------------------------------
__global__ void finalize_kernel(const int* __restrict__ num_pos,
                                const float* __restrict__ acc,  // [loss_l, pos_ce, neg_ce]
                                float* __restrict__ out) {
  int tid = threadIdx.x;  // 64 threads = 1 wave
  int np = num_pos[tid];
  for (int off = 32; off > 0; off >>= 1) np += __shfl_down(np, off, 64);
  if (tid == 0) {
    float N = fmaxf((float)np, 1.0f);
    out[0] = acc[0] / N;
    out[1] = (acc[1] + acc[2]) / N;
  }
}

}  // namespace

extern "C" void kernel_launch(void* const* d_in, const int* in_sizes, int n_in,
                              void* d_out, int out_size, void* d_ws, size_t ws_size,
                              hipStream_t stream) {
  const float* loc_data = (const float*)d_in[0];   // [B,P,4]
  const float* conf_data = (const float*)d_in[1];  // [B,P,81]
  const float* priors = (const float*)d_in[2];     // [P,4]
  const float* targets = (const float*)d_in[3];    // [B,T,5]
  float* out = (float*)d_out;                      // 2 floats

  // Workspace layout (needs ~8.1 MB):
  //   [0, 6.4M)       loss_c float[B*P]
  //   [6.4M, 8.0M)    conf_t u8[B*P]
  //   [8.0M, +256)    num_pos int[B]
  //   [+256, +320)    acc: loss_l, pos_ce, neg_ce
  char* ws = (char*)d_ws;
  float* loss_c = (float*)ws;
  unsigned char* conf_t = (unsigned char*)(ws + 6400000);
  int* num_pos = (int*)(ws + 8000000);
  float* acc = (float*)(ws + 8000256);

  hipMemsetAsync(acc, 0, 64, stream);
  hipLaunchKernelGGL(match_kernel, dim3(kB), dim3(256), 0, stream,
                     loc_data, priors, targets, conf_t, num_pos, acc + 0);
  hipLaunchKernelGGL(ce_kernel, dim3(kB * kP / kRowsPerBlk), dim3(256), 0, stream,
                     conf_data, conf_t, loss_c, acc + 1);
  hipLaunchKernelGGL(select_kernel, dim3(kB), dim3(256), 0, stream,
                     loss_c, num_pos, acc + 2);
  hipLaunchKernelGGL(finalize_kernel, dim3(1), dim3(64), 0, stream,
                     num_pos, acc, out);
}

// Round 2
// 834.401 us; speedup vs baseline: 1.5084x; 1.5084x over previous
//
#include <hip/hip_runtime.h>

namespace {

constexpr int kB = 64;
constexpr int kP = 25000;
constexpr int kT = 16;
constexpr int kC = 81;
constexpr int kRowsPerBlk = 64;            // ce_kernel rows per block
constexpr int kChunks = 16;                // prior chunks for match kernels
constexpr int kChunkP = (kP + kChunks - 1) / kChunks;  // 1563
constexpr float kThresh = 0.5f;

__device__ __forceinline__ float smooth_l1(float d) {
  float ad = fabsf(d);
  return ad < 1.0f ? 0.5f * d * d : ad - 0.5f;
}

// ---------------------------------------------------------------------------
// Kernel A1: per-prior best truth (computed ONCE), per-truth best prior via
// packed u64 atomicMax. Grid (kChunks, kB) x 256.
// mcode[b*P+p] = best_truth | (best_iou < 0.5 ? 0x80 : 0)
// best_prior[b*T+t] = atomicMax of (iou_bits << 32) | (0xFFFFFFFF - p)
//   -> max iou, ties prefer smaller p (first occurrence, matches jnp.argmax).
// ---------------------------------------------------------------------------
__global__ __launch_bounds__(256) void match1_kernel(
    const float* __restrict__ priors,     // [P,4] (cx,cy,w,h)
    const float* __restrict__ targets,    // [B,T,5]
    unsigned char* __restrict__ mcode,    // [B,P] out
    unsigned long long* __restrict__ best_prior) {  // [B,T], pre-zeroed
  const int chunk = blockIdx.x;
  const int b = blockIdx.y;
  const int tid = threadIdx.x;
  const int p0 = chunk * kChunkP;
  const int p1 = min(p0 + kChunkP, kP);

  __shared__ float tx0[kT], ty0[kT], tx1[kT], ty1[kT], tarea[kT];
  __shared__ float smax[kT][256];
  __shared__ int sidx[kT][256];

  if (tid < kT) {
    const float* tg = targets + (b * kT + tid) * 5;
    float x0 = tg[0], y0 = tg[1], x1 = tg[2], y1 = tg[3];
    tx0[tid] = x0; ty0[tid] = y0; tx1[tid] = x1; ty1[tid] = y1;
    tarea[tid] = (x1 - x0) * (y1 - y0);
  }
  __syncthreads();

  float bestv[kT];
  int besti[kT];
#pragma unroll
  for (int t = 0; t < kT; ++t) { bestv[t] = -1.0f; besti[t] = 0; }

  for (int p = p0 + tid; p < p1; p += 256) {
    float4 pr = reinterpret_cast<const float4*>(priors)[p];
    float px0 = pr.x - pr.z * 0.5f, py0 = pr.y - pr.w * 0.5f;
    float px1 = pr.x + pr.z * 0.5f, py1 = pr.y + pr.w * 0.5f;
    float parea = (px1 - px0) * (py1 - py0);
    float mv = -1.0f;
    int mt = 0;
#pragma unroll
    for (int t = 0; t < kT; ++t) {
      float lx = fmaxf(tx0[t], px0), ly = fmaxf(ty0[t], py0);
      float rx = fminf(tx1[t], px1), ry = fminf(ty1[t], py1);
      float w = fmaxf(rx - lx, 0.0f), h = fmaxf(ry - ly, 0.0f);
      float inter = w * h;
      float iou = inter / (tarea[t] + parea - inter);
      if (iou > bestv[t]) { bestv[t] = iou; besti[t] = p; }  // first idx wins
      if (iou > mv) { mv = iou; mt = t; }                    // first t wins
    }
    mcode[b * kP + p] = (unsigned char)(mt | (mv < kThresh ? 0x80 : 0));
  }
#pragma unroll
  for (int t = 0; t < kT; ++t) { smax[t][tid] = bestv[t]; sidx[t][tid] = besti[t]; }
  __syncthreads();
  for (int s = 128; s > 0; s >>= 1) {
    if (tid < s) {
#pragma unroll
      for (int t = 0; t < kT; ++t) {
        float v1 = smax[t][tid], v2 = smax[t][tid + s];
        int i1 = sidx[t][tid], i2 = sidx[t][tid + s];
        if (v2 > v1 || (v2 == v1 && i2 < i1)) { smax[t][tid] = v2; sidx[t][tid] = i2; }
      }
    }
    __syncthreads();
  }
  if (tid < kT) {
    // every thread in the chunk processed >= 1 prior, so smax >= 0 always
    unsigned long long pk = ((unsigned long long)__float_as_uint(smax[tid][0]) << 32) |
                            (unsigned long long)(0xFFFFFFFFu - (unsigned)sidx[tid][0]);
    atomicMax(&best_prior[b * kT + tid], pk);
  }
}

// ---------------------------------------------------------------------------
// Kernel A2: forcing + conf assignment + encode + smooth-L1 (no IoU recompute).
// Grid (kChunks, kB) x 256. code[] is read as mcode, overwritten as conf_t.
// ---------------------------------------------------------------------------
__global__ __launch_bounds__(256) void match2_kernel(
    const float* __restrict__ loc_data,   // [B,P,4]
    const float* __restrict__ priors,     // [P,4]
    const float* __restrict__ targets,    // [B,T,5]
    const unsigned long long* __restrict__ best_prior,  // [B,T]
    unsigned char* __restrict__ code,     // [B,P] in: mcode, out: conf_t
    int* __restrict__ num_pos,            // [B], pre-zeroed, atomicAdd
    float* __restrict__ loss_l_acc) {     // [1], pre-zeroed
  const int chunk = blockIdx.x;
  const int b = blockIdx.y;
  const int tid = threadIdx.x;
  const int p0 = chunk * kChunkP;
  const int p1 = min(p0 + kChunkP, kP);

  __shared__ int s_bp[kT];
  __shared__ float sx0[kT], sy0[kT], sx1[kT], sy1[kT], slab[kT];
  __shared__ float swf[4];
  __shared__ int swi[4];

  if (tid < kT) {
    s_bp[tid] = (int)(0xFFFFFFFFu -
                      (unsigned)(best_prior[b * kT + tid] & 0xFFFFFFFFull));
    const float* tg = targets + (b * kT + tid) * 5;
    sx0[tid] = tg[0]; sy0[tid] = tg[1]; sx1[tid] = tg[2]; sy1[tid] = tg[3];
    slab[tid] = tg[4];
  }
  __syncthreads();

  float lsum = 0.0f;
  int pcount = 0;
  for (int p = p0 + tid; p < p1; p += 256) {
    int c = code[b * kP + p];
    int mt = c & 0x0F;
    bool neg = (c & 0x80) != 0;
    bool forced = false;
#pragma unroll
    for (int j = 0; j < kT; ++j) {  // ascending j: last wins (torch loop order)
      if (s_bp[j] == p) { mt = j; forced = true; }
    }
    int conf = (!forced && neg) ? 0 : ((int)slab[mt] + 1);
    code[b * kP + p] = (unsigned char)conf;
    if (conf > 0) {
      ++pcount;
      float4 pr = reinterpret_cast<const float4*>(priors)[p];
      float mx0 = sx0[mt], my0 = sy0[mt], mx1 = sx1[mt], my1 = sy1[mt];
      float gcx = ((mx0 + mx1) * 0.5f - pr.x) / (0.1f * pr.z);
      float gcy = ((my0 + my1) * 0.5f - pr.y) / (0.1f * pr.w);
      float gw = logf((mx1 - mx0) / pr.z) / 0.2f;
      float gh = logf((my1 - my0) / pr.w) / 0.2f;
      float4 ld = reinterpret_cast<const float4*>(loc_data)[b * kP + p];
      lsum += smooth_l1(ld.x - gcx) + smooth_l1(ld.y - gcy) +
              smooth_l1(ld.z - gw) + smooth_l1(ld.w - gh);
    }
  }
  // wave reduce, then cross-wave via LDS
  for (int off = 32; off > 0; off >>= 1) {
    lsum += __shfl_down(lsum, off, 64);
    pcount += __shfl_down(pcount, off, 64);
  }
  if ((tid & 63) == 0) { swf[tid >> 6] = lsum; swi[tid >> 6] = pcount; }
  __syncthreads();
  if (tid == 0) {
    float lt = swf[0] + swf[1] + swf[2] + swf[3];
    int pt = swi[0] + swi[1] + swi[2] + swi[3];
    if (lt != 0.0f) atomicAdd(loss_l_acc, lt);
    if (pt != 0) atomicAdd(&num_pos[b], pt);
  }
}

// ---------------------------------------------------------------------------
// Kernel B: per-(b,p) cross-entropy via logsumexp. LDS-staged float4 loads,
// all 256 threads compute (4 lanes per row, quad shuffle reduce).
// Grid = B*P/kRowsPerBlk blocks x 256.
// ---------------------------------------------------------------------------
__global__ __launch_bounds__(256) void ce_kernel(
    const float* __restrict__ conf_data,      // [B*P, 81]
    const unsigned char* __restrict__ conf_t, // [B*P]
    float* __restrict__ loss_c,               // [B*P] out (0 at positives)
    float* __restrict__ pos_ce_acc) {         // [1] accumulate
  __shared__ float tile[kRowsPerBlk * kC];    // 20736 B
  __shared__ float swsum[4];
  const int tid = threadIdx.x;
  const long long base = (long long)blockIdx.x * (kRowsPerBlk * kC);
  const float4* src = reinterpret_cast<const float4*>(conf_data + base);
  float4* dst = reinterpret_cast<float4*>(tile);
#pragma unroll
  for (int i = 0; i < 6; ++i) {
    int idx = tid + i * 256;
    if (idx < kRowsPerBlk * kC / 4) dst[idx] = src[idx];
  }
  __syncthreads();

  const int r = tid >> 2;   // row within block, quads are wave-contiguous
  const int sub = tid & 3;
  const float* x = tile + r * kC;
  float m = -3.0e38f;
  for (int j = sub; j < kC; j += 4) m = fmaxf(m, x[j]);
  m = fmaxf(m, __shfl_xor(m, 1, 64));
  m = fmaxf(m, __shfl_xor(m, 2, 64));
  float s = 0.0f;
  for (int j = sub; j < kC; j += 4) s += __expf(x[j] - m);
  s += __shfl_xor(s, 1, 64);
  s += __shfl_xor(s, 2, 64);
  float posce = 0.0f;
  if (sub == 0) {
    const long long row = (long long)blockIdx.x * kRowsPerBlk + r;
    float lse = __logf(s) + m;
    int ct = conf_t[row];
    float ce = lse - x[ct];
    bool pos = ct > 0;
    loss_c[row] = pos ? 0.0f : ce;
    posce = pos ? ce : 0.0f;
  }
  for (int off = 32; off > 0; off >>= 1) posce += __shfl_down(posce, off, 64);
  if ((tid & 63) == 0) swsum[tid >> 6] = posce;
  __syncthreads();
  if (tid == 0) {
    float t = swsum[0] + swsum[1] + swsum[2] + swsum[3];
    if (t != 0.0f) atomicAdd(pos_ce_acc, t);  // positives are sparse
  }
}

// ---------------------------------------------------------------------------
// Kernel C: per-batch exact top-k sum of loss_c. Atomic-free: bitwise binary
// search for the k-th largest value's bit pattern (loss_c >= 0, so float bits
// are unsigned-monotone), values register-cached, then tie-corrected sum.
// ---------------------------------------------------------------------------
__global__ __launch_bounds__(256) void select_kernel(
    const float* __restrict__ loss_c,  // [B,P]
    const int* __restrict__ num_pos,   // [B]
    float* __restrict__ neg_ce_acc) {  // [1] accumulate
  const int b = blockIdx.x;
  const int tid = threadIdx.x;
  const int k = min(3 * num_pos[b], kP - 1);
  __shared__ int swi[4];
  __shared__ float swf[4];
  if (k <= 0) return;  // uniform branch per block

  constexpr int kV4 = kP / 4;                  // 6250
  constexpr int kPer = (kV4 + 255) / 256;      // 25
  const float4* v4 = reinterpret_cast<const float4*>(loss_c + (long long)b * kP);
  float4 lv[kPer];
#pragma unroll
  for (int j = 0; j < kPer; ++j) {
    int i = tid + j * 256;
    lv[j] = (i < kV4) ? v4[i] : float4{0.0f, 0.0f, 0.0f, 0.0f};
    // zero padding is safe: cand > 0 in every count, and 0 is never > ans
  }

  unsigned int ans = 0;
  for (int bit = 30; bit >= 0; --bit) {  // bit 31 never set (nonneg floats)
    const unsigned int cand = ans | (1u << bit);
    int cnt = 0;
#pragma unroll
    for (int j = 0; j < kPer; ++j) {
      cnt += (__float_as_uint(lv[j].x) >= cand) + (__float_as_uint(lv[j].y) >= cand) +
             (__float_as_uint(lv[j].z) >= cand) + (__float_as_uint(lv[j].w) >= cand);
    }
    for (int off = 32; off > 0; off >>= 1) cnt += __shfl_down(cnt, off, 64);
    if ((tid & 63) == 0) swi[tid >> 6] = cnt;
    __syncthreads();
    int tot = swi[0] + swi[1] + swi[2] + swi[3];  // uniform across block
    if (tot >= k) ans = cand;
    __syncthreads();
  }
  // ans = k-th largest value's bits. Sum strict-greater, pad with ties.
  float sum = 0.0f;
  int cgt = 0;
#pragma unroll
  for (int j = 0; j < kPer; ++j) {
    if (__float_as_uint(lv[j].x) > ans) { sum += lv[j].x; ++cgt; }
    if (__float_as_uint(lv[j].y) > ans) { sum += lv[j].y; ++cgt; }
    if (__float_as_uint(lv[j].z) > ans) { sum += lv[j].z; ++cgt; }
    if (__float_as_uint(lv[j].w) > ans) { sum += lv[j].w; ++cgt; }
  }
  for (int off = 32; off > 0; off >>= 1) {
    sum += __shfl_down(sum, off, 64);
    cgt += __shfl_down(cgt, off, 64);
  }
  if ((tid & 63) == 0) { swf[tid >> 6] = sum; swi[tid >> 6] = cgt; }
  __syncthreads();
  if (tid == 0) {
    float st = swf[0] + swf[1] + swf[2] + swf[3];
    int ct = swi[0] + swi[1] + swi[2] + swi[3];
    atomicAdd(neg_ce_acc, st + (float)(k - ct) * __uint_as_float(ans));
  }
}

// ---------------------------------------------------------------------------
// Kernel D: finalize the two scalar outputs.
// ---------------------------------------------------------------------------
__global__ void finalize_kernel(const int* __restrict__ num_pos,
                                const float* __restrict__ acc,  // [loss_l, pos_ce, neg_ce]
                                float* __restrict__ out) {
  int tid = threadIdx.x;  // 64 threads = 1 wave
  int np = num_pos[tid];
  for (int off = 32; off > 0; off >>= 1) np += __shfl_down(np, off, 64);
  if (tid == 0) {
    float N = fmaxf((float)np, 1.0f);
    out[0] = acc[0] / N;
    out[1] = (acc[1] + acc[2]) / N;
  }
}

}  // namespace

extern "C" void kernel_launch(void* const* d_in, const int* in_sizes, int n_in,
                              void* d_out, int out_size, void* d_ws, size_t ws_size,
                              hipStream_t stream) {
  const float* loc_data = (const float*)d_in[0];   // [B,P,4]
  const float* conf_data = (const float*)d_in[1];  // [B,P,81]
  const float* priors = (const float*)d_in[2];     // [P,4]
  const float* targets = (const float*)d_in[3];    // [B,T,5]
  float* out = (float*)d_out;                      // 2 floats

  // Workspace layout (~8.01 MB):
  //   [0, 6.4M)           loss_c float[B*P]
  //   [6.4M, 8.0M)        code u8[B*P]  (mcode from match1, conf_t after match2)
  //   [8.0M, +8192)       best_prior u64[B*T]          (zeroed)
  //   [+8192, +256)       num_pos int[B]               (zeroed)
  //   [+8448, +64)        acc: loss_l, pos_ce, neg_ce  (zeroed)
  char* ws = (char*)d_ws;
  float* loss_c = (float*)ws;
  unsigned char* code = (unsigned char*)(ws + 6400000);
  unsigned long long* best_prior = (unsigned long long*)(ws + 8000000);
  int* num_pos = (int*)(ws + 8008192);
  float* acc = (float*)(ws + 8008448);

  hipMemsetAsync(ws + 8000000, 0, 8512, stream);
  hipLaunchKernelGGL(match1_kernel, dim3(kChunks, kB), dim3(256), 0, stream,
                     priors, targets, code, best_prior);
  hipLaunchKernelGGL(match2_kernel, dim3(kChunks, kB), dim3(256), 0, stream,
                     loc_data, priors, targets, best_prior, code, num_pos, acc + 0);
  hipLaunchKernelGGL(ce_kernel, dim3(kB * kP / kRowsPerBlk), dim3(256), 0, stream,
                     conf_data, code, loss_c, acc + 1);
  hipLaunchKernelGGL(select_kernel, dim3(kB), dim3(256), 0, stream,
                     loss_c, num_pos, acc + 2);
  hipLaunchKernelGGL(finalize_kernel, dim3(1), dim3(64), 0, stream,
                     num_pos, acc, out);
}